// Round 4
// baseline (89.813 us; speedup 1.0000x reference)
//
#include <hip/hip_runtime.h>
#include <hip/hip_bf16.h>

// RoIPool max over boolean cell masks (harness bf16-ifies floats AND bools).
// B=8, C=256, H=W=64 (HW=4096), N=128 cells (16/image).
// R9 (post-mortem R8: in_sizes/out_size are ELEMENT counts (proven by the
// test's to_numpy(np.uint16,(out_size,))), so dtype is NOT host-knowable ->
// R8's host division picked MSIZE=1 for bf16 masks -> inf. Fix: restore the
// proven runtime byte-sniff detect, but SPECULATE so it never gates loads):
//   - every wave issues detect loads + bf16-interp data loads + counts in one
//     unconditional batch (bf16 interp is always in-bounds); ballot resolves
//     while loads are in flight; generic slow paths kept but never taken.
//   - keeps R8's verified fold-butterfly (17 swizzles, lane l&15 -> cell l&15;
//     hand-simulated on a 4-lane case) and __launch_bounds__(256,8).

#define HW    4096
#define BIMG  8
#define CCH   256
#define NCELL 128

__device__ __forceinline__ void cell_range(const int* counts, int b, int& start, int& cnt) {
    start = 0;
    for (int i = 0; i < b; ++i) start += counts[i];
    if (start > NCELL) start = NCELL;
    cnt = counts[b];
    // jnp.repeat(..., total_repeat_length=N) pads with the last value:
    if (b == BIMG - 1 && start + cnt < NCELL) cnt = NCELL - start;
    if (cnt > 16) cnt = 16;
    if (start + cnt > NCELL) cnt = NCELL - start;
    if (cnt < 0) cnt = 0;
}

// ---- kernel 1: bit-pack masks. grid 128 x 256 threads = 32768 = BIMG*HW ----
__global__ __launch_bounds__(256)
void pack_masks(const void* __restrict__ maskv,
                const int* __restrict__ counts,
                unsigned short* __restrict__ packed) {
    const int tid = threadIdx.x;
    const int l   = tid & 63;
    const int idx = blockIdx.x * 256 + tid;      // b*HW + p
    const int b = idx >> 12;
    const int p = idx & (HW - 1);

    // --- ALL loads issued up front, independent ---
    // (a) dtype detect: byte-lane OR over first 1 KiB (proven R3..R7)
    const unsigned* mw0 = (const unsigned*)maskv;
    const unsigned o0 = mw0[l * 4], o1 = mw0[l * 4 + 1],
                   o2 = mw0[l * 4 + 2], o3 = mw0[l * 4 + 3];
    // (b) speculative bf16-interp mask loads assuming start=b*16, cnt=16
    //     (actual harness layout; bf16 interp never exceeds the real buffer)
    const unsigned short* mh = (const unsigned short*)maskv + ((size_t)b * 16) * HW + p;
    unsigned short sv[16];
    #pragma unroll
    for (int j = 0; j < 16; ++j) sv[j] = mh[(size_t)j * HW];
    // (c) counts (scalar loads, gate nothing until the final select)
    int start, cnt;
    cell_range(counts, b, start, cnt);

    // detect resolves while (b) is still in flight
    unsigned ow = o0 | o1 | o2 | o3;
    #pragma unroll
    for (int d = 1; d < 64; d <<= 1) ow |= __shfl_xor(ow, d, 64);
    const unsigned or0 = ow & 0xFFu, or1 = (ow >> 8) & 0xFFu;
    int msize;
    if (or1 == 0)                        msize = 4;  // int32/f32 masks
    else if (or0 == 0x80 || or0 == 0x00) msize = 2;  // bf16 (3F80) / f16 (3C00)
    else                                 msize = 1;  // bool/uint8

    unsigned w = 0;
    if (msize == 2 && start == b * 16 && cnt == 16) {
        // fast path: consume speculative loads (always taken in practice)
        #pragma unroll
        for (int j = 0; j < 16; ++j) w |= (sv[j] ? 1u : 0u) << j;
    } else if (msize == 2) {
        const unsigned short* m2 = (const unsigned short*)maskv + (size_t)start * HW + p;
        for (int j = 0; j < cnt; ++j) w |= (m2[(size_t)j * HW] ? 1u : 0u) << j;
    } else if (msize == 4) {
        const unsigned* m4 = (const unsigned*)maskv + (size_t)start * HW + p;
        for (int j = 0; j < cnt; ++j) w |= (m4[(size_t)j * HW] ? 1u : 0u) << j;
    } else {
        const unsigned char* m1 = (const unsigned char*)maskv + (size_t)start * HW + p;
        for (int j = 0; j < cnt; ++j) w |= (m1[(size_t)j * HW] ? 1u : 0u) << j;
    }
    packed[idx] = (unsigned short)w;
}

// ---- kernel 2: one 256-thr block per (b, c). grid (256, 8) ----
__global__ __launch_bounds__(256, 8)
void roipool_main(const void* __restrict__ featv,
                  const unsigned short* __restrict__ packed,
                  const int* __restrict__ counts,
                  void* __restrict__ outv) {
    const int c   = blockIdx.x;
    const int b   = blockIdx.y;
    const int tid = threadIdx.x;
    const int l   = tid & 63;      // lane
    const int wv  = tid >> 6;      // wave 0..3
    const float NEG = -__builtin_inff();
    const unsigned NEGI = 0xFF800000u;   // f32 -inf bits

    const int p0 = tid * 16;   // this thread's 16 pixels

    // --- ALL loads issued up front, independent ---
    // (a) speculative bf16-interp feature loads (in-bounds for f32 data too:
    //     bf16 interp touches only the first half of an f32 buffer)
    const unsigned short* fp16 = (const unsigned short*)featv
                               + (((size_t)(b * CCH + c)) << 12) + p0;
    uint4 f0 = *(const uint4*)(fp16);
    uint4 f1 = *(const uint4*)(fp16 + 8);
    // (b) packed masks: 16 uint16 = 32 B; dword k holds masks of px (2k,2k+1)
    uint4 pa = *(const uint4*)(packed + ((size_t)b << 12) + p0);
    uint4 pb = *(const uint4*)(packed + ((size_t)b << 12) + p0 + 8);
    // (c) dtype detect dword (first 256 B of features)
    const unsigned w0 = ((const unsigned*)featv)[l];
    // (d) counts (gates only the final store)
    int start, cnt;
    cell_range(counts, b, start, cnt);

    // detect resolves while (a)/(b) are in flight: bf16 iff byte1 looks like
    // a bf16 exponent byte across the wave (proven R5..R7 heuristic)
    const unsigned eb = (w0 >> 8) & 0x7F;
    const unsigned long long bm = __ballot(eb >= 0x3B && eb <= 0x41);
    const int fbf16 = (__popcll(bm) >= 48);

    const unsigned pmw[8] = {pa.x, pa.y, pa.z, pa.w, pb.x, pb.y, pb.z, pb.w};

    // features as f32 bit patterns: pair k = pixels (2k, 2k+1)
    unsigned pe[8], po[8];
    if (fbf16) {
        const unsigned w8[8] = {f0.x, f0.y, f0.z, f0.w, f1.x, f1.y, f1.z, f1.w};
        #pragma unroll
        for (int k = 0; k < 8; ++k) {
            pe[k] = w8[k] << 16;          // even px as f32 bits
            po[k] = w8[k] & 0xFFFF0000u;  // odd px as f32 bits
        }
    } else {
        // cold path (never taken for this harness): reload as f32
        const float* fp = (const float*)featv + (((size_t)(b * CCH + c)) << 12) + p0;
        #pragma unroll
        for (int q = 0; q < 4; ++q) {
            uint4 a = *(const uint4*)(fp + q * 4);
            pe[q * 2]     = a.x; po[q * 2]     = a.y;
            pe[q * 2 + 1] = a.z; po[q * 2 + 1] = a.w;
        }
    }

    float vmax[16];
    #pragma unroll
    for (int j = 0; j < 16; ++j) vmax[j] = NEG;

    #pragma unroll
    for (int k = 0; k < 8; ++k) {
        const unsigned fe = pe[k], fo = po[k];
        const unsigned mw = pmw[k];   // bits 0..15: px 2k; bits 16..31: px 2k+1
        #pragma unroll
        for (int j = 0; j < 16; ++j) {
            unsigned m0 = (unsigned)(((int)(mw << (31 - j))) >> 31);  // bfe_i32 bit j
            unsigned m1 = (unsigned)(((int)(mw << (15 - j))) >> 31);  // bit j+16
            float s0 = __uint_as_float((fe & m0) | (NEGI & ~m0));     // bfi_b32
            float s1 = __uint_as_float((fo & m1) | (NEGI & ~m1));
            vmax[j] = fmaxf(fmaxf(vmax[j], s0), s1);                  // max3_f32
        }
    }

    // Fold-as-you-go butterfly (verified by 4-lane hand simulation): each step
    // halves the value set; lane bit k picks which cell half stays. After 4
    // folds lane l holds cell (l&15) over its 16-lane group; d=16,32 merge
    // the 4 duplicate groups. 17 swizzles total.
    float v8[8];
    {
        const bool s = (l & 1);
        #pragma unroll
        for (int j = 0; j < 8; ++j) {
            float snd = s ? vmax[2*j]   : vmax[2*j+1];
            float mne = s ? vmax[2*j+1] : vmax[2*j];
            v8[j] = fmaxf(mne, __shfl_xor(snd, 1, 64));   // cell 2j + (l&1)
        }
    }
    float v4[4];
    {
        const bool s = (l >> 1) & 1;
        #pragma unroll
        for (int j = 0; j < 4; ++j) {
            float snd = s ? v8[2*j]   : v8[2*j+1];
            float mne = s ? v8[2*j+1] : v8[2*j];
            v4[j] = fmaxf(mne, __shfl_xor(snd, 2, 64));   // cell 4j + (l&3)
        }
    }
    float v2[2];
    {
        const bool s = (l >> 2) & 1;
        #pragma unroll
        for (int j = 0; j < 2; ++j) {
            float snd = s ? v4[2*j]   : v4[2*j+1];
            float mne = s ? v4[2*j+1] : v4[2*j];
            v2[j] = fmaxf(mne, __shfl_xor(snd, 4, 64));   // cell 8j + (l&7)
        }
    }
    float v1;
    {
        const bool s = (l >> 3) & 1;
        float snd = s ? v2[0] : v2[1];
        float mne = s ? v2[1] : v2[0];
        v1 = fmaxf(mne, __shfl_xor(snd, 8, 64));          // cell = l & 15
    }
    v1 = fmaxf(v1, __shfl_xor(v1, 16, 64));
    v1 = fmaxf(v1, __shfl_xor(v1, 32, 64));

    // cross-wave combine: 4 waves x 16 cells, ONE barrier, 320 B LDS.
    __shared__ float red[4][16];
    if (l < 16) red[wv][l] = v1;
    __syncthreads();
    if (tid < 16) {
        float m = fmaxf(fmaxf(red[0][tid], red[1][tid]),
                        fmaxf(red[2][tid], red[3][tid]));
        if (tid < cnt) {
            const size_t oi = (size_t)(start + tid) * CCH + c;
            if (fbf16) ((__hip_bfloat16*)outv)[oi] = __float2bfloat16(m);
            else       ((float*)outv)[oi]          = m;
        }
    }
}

extern "C" void kernel_launch(void* const* d_in, const int* in_sizes, int n_in,
                              void* d_out, int out_size, void* d_ws, size_t ws_size,
                              hipStream_t stream) {
    const void* feat  = d_in[0];
    const void* masks = d_in[1];
    const int* counts = (const int*)d_in[2];
    unsigned short* packed = (unsigned short*)d_ws;   // 8*4096*2 = 64 KiB

    pack_masks<<<(BIMG * HW) / 256, 256, 0, stream>>>(masks, counts, packed);

    dim3 grid(CCH, BIMG);   // 2048 blocks, one per (b, c)
    roipool_main<<<grid, 256, 0, stream>>>(feat, packed, counts, d_out);
}